// Round 3
// baseline (308.851 us; speedup 1.0000x reference)
//
#include <hip/hip_runtime.h>
#include <math.h>

// Problem constants
#define NB   64
#define TT   2048
// Tail-window truncation: output = x[:, 2047]; the only temporal coupling is
// the LIF membrane (decay 0.5/step + hard reset). v(T0)=0 direct error at
// 2047 is 0.5^63; validated in prior rounds (TW=192 matched full scan).
#define TW   64
#define T0   (TT - TW)     // 1984
#define NR   (NB * TW)     // 4096 active rows

__device__ __forceinline__ float gelu_exact(float x) {
    return 0.5f * x * (1.0f + erff(x * 0.7071067811865476f));
}

// 4-block per-batch barrier. Monotonic counter per batch; target = 4*phase.
// Release on the add flushes this XCD's dirty L2 to the device coherence
// point; acquire after the spin invalidates L1/L2 so partner writes are seen.
// All written intermediates are read via VECTOR loads only (no s_load of
// mutable data), so the scalar cache never holds stale kernel-written data.
__device__ __forceinline__ void batch_barrier(int* cnt, int target) {
    __syncthreads();   // each wave drains its own stores (vmcnt) before s_barrier
    if (threadIdx.x == 0) {
        __hip_atomic_fetch_add(cnt, 1, __ATOMIC_RELEASE, __HIP_MEMORY_SCOPE_AGENT);
        while (__hip_atomic_load(cnt, __ATOMIC_RELAXED, __HIP_MEMORY_SCOPE_AGENT) < target)
            __builtin_amdgcn_s_sleep(1);
        __builtin_amdgcn_fence(__ATOMIC_ACQUIRE, "agent");
    }
    __syncthreads();
}

// 256 blocks = 64 batches x 4 quarters; bid = q*64 + b so the 4 partners of a
// batch share an XCD (bid % 8 equal) -- perf heuristic only, never correctness.
// Block (b,q): GEMM/LN phases own 16 rows (t in [q*16,q*16+16)); LIF phases own
// a column slice (64 cols of H, 32 cols of Y/X) across all 64 t's.
// LDS (64KB = 16384 floats), timeshared:
//   proj:  G[16][64] @ [0,1024) ; pw2[64][128] @ [2048,10240)
//   fc1:   Wstage[32][256] @ [0,8192) ; Xq[16][128] @ [8192,10240)
//   fc2:   Wstage[64][128] @ [0,8192) ; Sq[16][256] @ [8192,12288)
//   lif1:  Hcols[64][64] @ [0,4096)
//   lif2:  Ycols[64][32] @ [0,2048) ; Xcols[64][32] @ [2048,4096)
__global__ void __launch_bounds__(512) fused_kernel(
    const float* __restrict__ hist,
    const float* __restrict__ pw1, const float* __restrict__ pb1,
    const float* __restrict__ pw2, const float* __restrict__ pb2,
    const float* __restrict__ fc1w, const float* __restrict__ fc1b,
    const float* __restrict__ n1g,  const float* __restrict__ n1b,
    const float* __restrict__ fc2w, const float* __restrict__ fc2b,
    const float* __restrict__ n2g,  const float* __restrict__ n2b,
    float* __restrict__ Xb, float* __restrict__ Hb,
    float* __restrict__ Sb, float* __restrict__ Yb,
    int* __restrict__ cnt, float* __restrict__ out)
{
    __shared__ float LB[16384];
    const int tid  = threadIdx.x;
    const int wave = tid >> 6, lane = tid & 63;
    const int b = blockIdx.x & 63, q = blockIdx.x >> 6;
    const int R  = b * 64;           // batch global row base
    const int tq = q * 16;           // this block's quarter-row offset
    int* bcnt = cnt + b;
    int bar = 0;

    // ---------------- proj1: G = gelu(hist @ pw1 + pb1) for own 16 rows -----
    for (int j = tid; j < 1024; j += 512) {
        int row = j >> 6, col = j & 63;
        float4 h = *(const float4*)(hist + ((size_t)b*TT + T0 + tq + row) * 4);
        LB[j] = gelu_exact(pb1[col] + h.x*pw1[col] + h.y*pw1[64+col]
                           + h.z*pw1[128+col] + h.w*pw1[192+col]);
    }
    for (int i = tid; i < 2048; i += 512)
        ((float4*)(LB + 2048))[i] = ((const float4*)pw2)[i];
    __syncthreads();
    // ---------------- proj2: X0 rows = G @ pw2 + pb2 (8 waves x 2 rows) -----
    {
        float2 bv = ((const float2*)pb2)[lane];
        float2 acc[2];
        acc[0] = make_float2(0.f, 0.f); acc[1] = make_float2(0.f, 0.f);
        #pragma unroll 2
        for (int k4 = 0; k4 < 16; ++k4) {
            float4 xr[2];
            #pragma unroll
            for (int r = 0; r < 2; ++r)
                xr[r] = *(const float4*)(LB + (wave*2 + r)*64 + k4*4);  // uniform
            #pragma unroll
            for (int kk = 0; kk < 4; ++kk) {
                float2 w = ((const float2*)(LB + 2048 + (k4*4 + kk)*128))[lane];
                #pragma unroll
                for (int r = 0; r < 2; ++r) {
                    float xv = ((const float*)&xr[r])[kk];
                    acc[r].x += xv * w.x;
                    acc[r].y += xv * w.y;
                }
            }
        }
        __syncthreads();             // all waves done with G/pw2 in LDS
        #pragma unroll
        for (int r = 0; r < 2; ++r) {
            int row = wave*2 + r;
            float2 o; o.x = acc[r].x + bv.x; o.y = acc[r].y + bv.y;
            ((float2*)(LB + 8192 + row*128))[lane] = o;                 // Xq LDS
            ((float2*)(Xb + (size_t)(R + tq + row)*128))[lane] = o;     // X0 global
        }
    }

    #pragma unroll 1
    for (int l = 0; l < 4; ++l) {
        const float* __restrict__ Xl = Xb + (size_t)l     * NR * 128;
        float*       __restrict__ Xo = Xb + (size_t)(l+1) * NR * 128;
        float*       __restrict__ Hl = Hb + (size_t)l * NR * 256;
        float*       __restrict__ Sl = Sb + (size_t)l * NR * 256;
        float*       __restrict__ Yl = Yb + (size_t)l * NR * 128;

        // ---- fc1 + LN: own 16 rows x 256 cols, K=128 (4 W-stages of 32k) ---
        if (l > 0) {                 // Xq for l=0 was produced by proj2 in LDS
            __syncthreads();         // prior LDS users done
            ((float4*)(LB + 8192))[tid] =
                ((const float4*)(Xl + (size_t)(R + tq)*128))[tid];  // 512 f4
        }
        {
            const float* W1 = fc1w + (size_t)l * 128 * 256;
            float4 acc1[2];
            acc1[0] = make_float4(0.f,0.f,0.f,0.f);
            acc1[1] = make_float4(0.f,0.f,0.f,0.f);
            for (int s = 0; s < 4; ++s) {
                __syncthreads();
                for (int i = tid; i < 2048; i += 512)
                    ((float4*)LB)[i] = ((const float4*)(W1 + s*8192))[i];
                __syncthreads();
                #pragma unroll 2
                for (int k4 = 0; k4 < 8; ++k4) {
                    float4 xr[2];
                    #pragma unroll
                    for (int r = 0; r < 2; ++r)
                        xr[r] = *(const float4*)(LB + 8192 + (wave*2 + r)*128
                                                 + s*32 + k4*4);        // uniform
                    #pragma unroll
                    for (int kk = 0; kk < 4; ++kk) {
                        float4 w = ((const float4*)(LB + (k4*4 + kk)*256))[lane];
                        #pragma unroll
                        for (int r = 0; r < 2; ++r) {
                            float xv = ((const float*)&xr[r])[kk];
                            acc1[r].x += xv * w.x; acc1[r].y += xv * w.y;
                            acc1[r].z += xv * w.z; acc1[r].w += xv * w.w;
                        }
                    }
                }
            }
            float4 bv  = ((const float4*)(fc1b + l*256))[lane];
            float4 gv  = ((const float4*)(n1g  + l*256))[lane];
            float4 btv = ((const float4*)(n1b  + l*256))[lane];
            #pragma unroll
            for (int r = 0; r < 2; ++r) {
                float4 a = acc1[r];
                a.x += bv.x; a.y += bv.y; a.z += bv.z; a.w += bv.w;
                float s = a.x + a.y + a.z + a.w;
                #pragma unroll
                for (int m = 1; m < 64; m <<= 1) s += __shfl_xor(s, m, 64);
                float mean = s * (1.0f/256.0f);
                float dx = a.x - mean, dy = a.y - mean, dz = a.z - mean, dw = a.w - mean;
                float q2 = dx*dx + dy*dy + dz*dz + dw*dw;
                #pragma unroll
                for (int m = 1; m < 64; m <<= 1) q2 += __shfl_xor(q2, m, 64);
                float inv = 1.0f / sqrtf(q2 * (1.0f/256.0f) + 1e-5f);
                float4 o;
                o.x = dx*inv*gv.x + btv.x; o.y = dy*inv*gv.y + btv.y;
                o.z = dz*inv*gv.z + btv.z; o.w = dw*inv*gv.w + btv.w;
                ((float4*)(Hl + (size_t)(R + tq + wave*2 + r)*256))[lane] = o;
            }
        }
        batch_barrier(bcnt, 4*(++bar));       // H complete for batch b

        // ---- LIF1: own 64 columns, chains over all 64 t's (LDS-staged) -----
        for (int i = tid; i < 4096; i += 512) {
            int t = i >> 6, dd = i & 63;
            LB[i] = Hl[(size_t)(R + t)*256 + q*64 + dd];
        }
        __syncthreads();
        if (tid < 64) {
            float* sp = Sl + (size_t)R*256 + q*64 + tid;
            float v = 0.f;
            #pragma unroll 16
            for (int t = 0; t < 64; ++t) {
                float x = LB[t*64 + tid];
                v += (x - v) * 0.5f;
                bool s = (v >= 1.f);
                sp[(size_t)t*256] = s ? 1.f : 0.f;
                v = s ? 0.f : v;
            }
        }
        batch_barrier(bcnt, 4*(++bar));       // spikes complete for batch b

        // ---- fc2 + LN: own 16 rows x 128 cols, K=256 (4 W-stages of 64k) ---
        {
            for (int i = tid; i < 1024; i += 512)     // stage Sq 16x256
                ((float4*)(LB + 8192))[i] =
                    ((const float4*)(Sl + (size_t)(R + tq)*256))[i];
            const float* W2 = fc2w + (size_t)l * 256 * 128;
            float2 acc2[2];
            acc2[0] = make_float2(0.f, 0.f); acc2[1] = make_float2(0.f, 0.f);
            for (int s = 0; s < 4; ++s) {
                __syncthreads();
                for (int i = tid; i < 2048; i += 512)
                    ((float4*)LB)[i] = ((const float4*)(W2 + s*8192))[i];
                __syncthreads();
                #pragma unroll 2
                for (int k4 = 0; k4 < 16; ++k4) {
                    float4 xr[2];
                    #pragma unroll
                    for (int r = 0; r < 2; ++r)
                        xr[r] = *(const float4*)(LB + 8192 + (wave*2 + r)*256
                                                 + s*64 + k4*4);        // uniform
                    #pragma unroll
                    for (int kk = 0; kk < 4; ++kk) {
                        float2 w = ((const float2*)(LB + (k4*4 + kk)*128))[lane];
                        #pragma unroll
                        for (int r = 0; r < 2; ++r) {
                            float xv = ((const float*)&xr[r])[kk];
                            acc2[r].x += xv * w.x;
                            acc2[r].y += xv * w.y;
                        }
                    }
                }
            }
            float2 bv  = ((const float2*)(fc2b + l*128))[lane];
            float2 gv  = ((const float2*)(n2g  + l*128))[lane];
            float2 btv = ((const float2*)(n2b  + l*128))[lane];
            #pragma unroll
            for (int r = 0; r < 2; ++r) {
                float2 a = acc2[r];
                a.x += bv.x; a.y += bv.y;
                float s = a.x + a.y;
                #pragma unroll
                for (int m = 1; m < 64; m <<= 1) s += __shfl_xor(s, m, 64);
                float mean = s * (1.0f/128.0f);
                float dx = a.x - mean, dy = a.y - mean;
                float qq = dx*dx + dy*dy;
                #pragma unroll
                for (int m = 1; m < 64; m <<= 1) qq += __shfl_xor(qq, m, 64);
                float inv = 1.0f / sqrtf(qq * (1.0f/128.0f) + 1e-5f);
                float2 o;
                o.x = dx*inv*gv.x + btv.x;
                o.y = dy*inv*gv.y + btv.y;
                ((float2*)(Yl + (size_t)(R + tq + wave*2 + r)*128))[lane] = o;
            }
        }
        batch_barrier(bcnt, 4*(++bar));       // Y complete for batch b

        // ---- LIF2 + residual: own 32 columns over all 64 t's ---------------
        for (int i = tid; i < 2048; i += 512) {
            int t = i >> 5, nn = i & 31;
            LB[i]        = Yl[(size_t)(R + t)*128 + q*32 + nn];
            LB[2048 + i] = Xl[(size_t)(R + t)*128 + q*32 + nn];
        }
        __syncthreads();
        if (tid < 32) {
            int n = q*32 + tid;
            float* xo = Xo + (size_t)R*128 + n;
            float v = 0.f, xlast = 0.f;
            #pragma unroll 16
            for (int t = 0; t < 64; ++t) {
                float y = LB[t*32 + tid];
                v += (y - v) * 0.5f;
                bool s = (v >= 1.f);
                float xn = LB[2048 + t*32 + tid] + (s ? 1.f : 0.f);
                if (l < 3) xo[(size_t)t*128] = xn;
                xlast = xn;
                v = s ? 0.f : v;
            }
            if (l == 3) out[b*128 + n] = xlast;    // row t=2047 per (b,n)
        }
        if (l < 3) batch_barrier(bcnt, 4*(++bar)); // X(l+1) complete
    }
}

extern "C" void kernel_launch(void* const* d_in, const int* in_sizes, int n_in,
                              void* d_out, int out_size, void* d_ws, size_t ws_size,
                              hipStream_t stream) {
    const float* hist = (const float*)d_in[0];
    const float* pw1  = (const float*)d_in[1];
    const float* pb1  = (const float*)d_in[2];
    const float* pw2  = (const float*)d_in[3];
    const float* pb2  = (const float*)d_in[4];
    const float* fc1w = (const float*)d_in[5];
    const float* fc1b = (const float*)d_in[6];
    const float* n1g  = (const float*)d_in[7];
    const float* n1b  = (const float*)d_in[8];
    const float* fc2w = (const float*)d_in[9];
    const float* fc2b = (const float*)d_in[10];
    const float* n2g  = (const float*)d_in[11];
    const float* n2b  = (const float*)d_in[12];
    float* out = (float*)d_out;

    char* ws = (char*)d_ws;
    float* Xb = (float*)ws;                      // 5 x [NR,128] = 10 MiB
    float* Hb = (float*)(ws + (16ull << 20));    // 4 x [NR,256] = 16 MiB
    float* Sb = (float*)(ws + (32ull << 20));    // 4 x [NR,256] = 16 MiB
    float* Yb = (float*)(ws + (48ull << 20));    // 4 x [NR,128] =  8 MiB
    int*   cnt = (int*)(ws + (60ull << 20));     // 64 batch counters

    hipMemsetAsync(cnt, 0, 64 * sizeof(int), stream);
    fused_kernel<<<256, 512, 0, stream>>>(hist, pw1, pb1, pw2, pb2,
                                          fc1w, fc1b, n1g, n1b,
                                          fc2w, fc2b, n2g, n2b,
                                          Xb, Hb, Sb, Yb, cnt, out);
}

// Round 4
// 287.799 us; speedup vs baseline: 1.0731x; 1.0731x over previous
//
#include <hip/hip_runtime.h>
#include <math.h>

// Problem constants
#define NB   64
#define TT   2048
// Tail-window truncation: output = x[:, 2047]; the only temporal coupling is
// the LIF membrane (decay 0.5/step + hard reset). v(T0)=0 direct error at
// 2047 is 0.5^63; validated in prior rounds (TW=192 matched full scan).
#define TW   64
#define T0   (TT - TW)     // 1984
#define NR   (NB * TW)     // 4096 active rows

typedef float v4f __attribute__((ext_vector_type(4)));

// LDS float offsets (total 13184 floats = 51.5KB)
#define LB_W    0       // [0,8192): 32KB fc1 W chunk (32 k-rows x 256)
#define LB_G    0       // proj: G[64][64] @ [0,4096)
#define LB_PW2  4096    // proj: pw2 @ [4096,12288)
#define LB_MSK  12288   // spike masks: u64[64 t][4] = 512 floats
#define LB_V1   12800   // LIF1 v-state: 256 floats
#define LB_V2   13056   // LIF2 v-state: 128 floats
#define LB_TOT  13184

__device__ __forceinline__ float gelu_exact(float x) {
    return 0.5f * x * (1.0f + erff(x * 0.7071067811865476f));
}
__device__ __forceinline__ unsigned long long rfl64(unsigned long long x) {
    unsigned lo = __builtin_amdgcn_readfirstlane((unsigned)x);
    unsigned hi = __builtin_amdgcn_readfirstlane((unsigned)(x >> 32));
    return ((unsigned long long)hi << 32) | lo;
}

// One block per batch (64 blocks x 512 threads). All math is bit-identical to
// the round-2 kernel (same tiling, same accumulation order, same LN trees):
//  - fc2 is computed sparsely from LIF1 spike bitmasks, iterating d ascending
//    with exact-zero conditional adds (fp-identical to dense fma with x=0/1).
//  - LIF1/LIF2 run on in-register GEMM tiles: wave s owns rows 8s..8s+7, so
//    the time chain is 8 sync-separated wave stages; only the v-state (<=1KB)
//    passes through LDS. H, Y, and spikes never touch global memory.
//  - fc1 W chunks (4 x 32KB) are register-prefetched ahead of the K-loop.
__global__ void __launch_bounds__(512) fused_kernel(
    const float* __restrict__ hist,
    const float* __restrict__ pw1, const float* __restrict__ pb1,
    const float* __restrict__ pw2, const float* __restrict__ pb2,
    const float* __restrict__ fc1w, const float* __restrict__ fc1b,
    const float* __restrict__ n1g,  const float* __restrict__ n1b,
    const float* __restrict__ fc2w, const float* __restrict__ fc2b,
    const float* __restrict__ n2g,  const float* __restrict__ n2b,
    const float* __restrict__ XbR, float* __restrict__ XbW,
    float* __restrict__ out)
{
    __shared__ float LB[LB_TOT];
    unsigned long long* MSK = (unsigned long long*)&LB[LB_MSK];
    const int tid = threadIdx.x, wave = tid >> 6, lane = tid & 63;
    const int b = blockIdx.x;
    const int row0 = wave * 8;           // block-local rows owned by this wave

    // ---------------- proj1: G = gelu(hist @ pw1 + pb1) -> LB; stage pw2 ----
    {
        const float* hb = hist + ((size_t)b * TT + T0) * 4;
        float w0 = pw1[lane], w1 = pw1[64+lane], w2 = pw1[128+lane], w3 = pw1[192+lane];
        float bb = pb1[lane];
        #pragma unroll
        for (int r = 0; r < 8; ++r) {
            int t = row0 + r;
            float4 h = *(const float4*)(hb + t*4);
            LB[LB_G + t*64 + lane] = gelu_exact(bb + h.x*w0 + h.y*w1 + h.z*w2 + h.w*w3);
        }
        for (int i = tid; i < 2048; i += 512)
            ((float4*)(LB + LB_PW2))[i] = ((const float4*)pw2)[i];
    }
    __syncthreads();
    // ---------------- proj2: X0 = G @ pw2 + pb2 -----------------------------
    {
        float* X0 = XbW + (size_t)b * TW * 128;
        float2 bv = ((const float2*)pb2)[lane];
        float2 acc[8];
        #pragma unroll
        for (int r = 0; r < 8; ++r) acc[r] = make_float2(0.f, 0.f);
        #pragma unroll 2
        for (int k4 = 0; k4 < 16; ++k4) {
            float4 xr[8];
            #pragma unroll
            for (int r = 0; r < 8; ++r)
                xr[r] = *(const float4*)(LB + LB_G + (row0 + r)*64 + k4*4);
            #pragma unroll
            for (int kk = 0; kk < 4; ++kk) {
                float2 w = ((const float2*)(LB + LB_PW2 + (k4*4 + kk)*128))[lane];
                #pragma unroll
                for (int r = 0; r < 8; ++r) {
                    float xv = ((const float*)&xr[r])[kk];
                    acc[r].x += xv * w.x;
                    acc[r].y += xv * w.y;
                }
            }
        }
        #pragma unroll
        for (int r = 0; r < 8; ++r) {
            float2 o; o.x = acc[r].x + bv.x; o.y = acc[r].y + bv.y;
            ((float2*)(X0 + (size_t)(row0 + r)*128))[lane] = o;
        }
    }

    // prefetch layer-0 fc1 W chunk 0 into registers
    v4f wr0, wr1, wr2, wr3;
    {
        const v4f* Wn = (const v4f*)fc1w;
        wr0 = Wn[tid]; wr1 = Wn[tid+512]; wr2 = Wn[tid+1024]; wr3 = Wn[tid+1536];
    }

    #pragma unroll 1
    for (int l = 0; l < 4; ++l) {
        const float* Xl  = XbR + ((size_t)l*NR + b*TW) * 128;
        float*       Xo  = XbW + ((size_t)(l+1)*NR + b*TW) * 128;
        const float* W1  = fc1w + (size_t)l * 32768;
        const float* W2g = fc2w + (size_t)l * 32768;

        // ---- fc1: H = X @ W1, 4 reg-prefetched 32KB W chunks ----
        float4 acc[8];
        #pragma unroll
        for (int r = 0; r < 8; ++r) acc[r] = make_float4(0.f,0.f,0.f,0.f);
        #pragma unroll 1
        for (int c = 0; c < 4; ++c) {
            __syncthreads();                       // prev LB readers done
            ((v4f*)LB)[tid]      = wr0;
            ((v4f*)LB)[tid+512]  = wr1;
            ((v4f*)LB)[tid+1024] = wr2;
            ((v4f*)LB)[tid+1536] = wr3;
            __syncthreads();
            if (c < 3) {                           // issue next chunk early
                const v4f* Wn = (const v4f*)(W1 + (c+1)*8192);
                wr0 = Wn[tid]; wr1 = Wn[tid+512]; wr2 = Wn[tid+1024]; wr3 = Wn[tid+1536];
            }
            const float* xc = Xl + c*32;
            #pragma unroll 2
            for (int k4 = 0; k4 < 8; ++k4) {
                float4 xr[8];
                #pragma unroll
                for (int r = 0; r < 8; ++r)
                    xr[r] = *(const float4*)(xc + (size_t)(row0 + r)*128 + k4*4);
                #pragma unroll
                for (int kk = 0; kk < 4; ++kk) {
                    float4 w = ((const float4*)(LB + (k4*4 + kk)*256))[lane];
                    #pragma unroll
                    for (int r = 0; r < 8; ++r) {
                        float xv = ((const float*)&xr[r])[kk];
                        acc[r].x += xv * w.x; acc[r].y += xv * w.y;
                        acc[r].z += xv * w.z; acc[r].w += xv * w.w;
                    }
                }
            }
        }
        // ---- LN1 (round-2 tree) -> H stays in acc ----
        {
            float4 bv  = ((const float4*)(fc1b + l*256))[lane];
            float4 gv  = ((const float4*)(n1g  + l*256))[lane];
            float4 btv = ((const float4*)(n1b  + l*256))[lane];
            #pragma unroll
            for (int r = 0; r < 8; ++r) {
                float4 a = acc[r];
                a.x += bv.x; a.y += bv.y; a.z += bv.z; a.w += bv.w;
                float s = a.x + a.y + a.z + a.w;
                #pragma unroll
                for (int m = 1; m < 64; m <<= 1) s += __shfl_xor(s, m, 64);
                float mean = s * (1.0f/256.0f);
                float dx = a.x-mean, dy = a.y-mean, dz = a.z-mean, dw = a.w-mean;
                float q2 = dx*dx + dy*dy + dz*dz + dw*dw;
                #pragma unroll
                for (int m = 1; m < 64; m <<= 1) q2 += __shfl_xor(q2, m, 64);
                float inv = 1.0f / sqrtf(q2 * (1.0f/256.0f) + 1e-5f);
                acc[r].x = dx*inv*gv.x + btv.x; acc[r].y = dy*inv*gv.y + btv.y;
                acc[r].z = dz*inv*gv.z + btv.z; acc[r].w = dw*inv*gv.w + btv.w;
            }
        }
        // ---- LIF1: serial wave-handoff over t; spikes -> ballot masks ----
        #pragma unroll 1
        for (int s = 0; s < 8; ++s) {
            if (wave == s) {
                float4 v;
                if (s == 0) v = make_float4(0.f,0.f,0.f,0.f);
                else        v = *(float4*)&LB[LB_V1 + lane*4];
                #pragma unroll
                for (int i = 0; i < 8; ++i) {
                    int t = s*8 + i;
                    float4 h = acc[i];
                    v.x += (h.x - v.x) * 0.5f;  v.y += (h.y - v.y) * 0.5f;
                    v.z += (h.z - v.z) * 0.5f;  v.w += (h.w - v.w) * 0.5f;
                    bool s0 = v.x >= 1.f, s1 = v.y >= 1.f, s2 = v.z >= 1.f, s3 = v.w >= 1.f;
                    unsigned long long b0 = __ballot(s0), b1 = __ballot(s1);
                    unsigned long long b2 = __ballot(s2), b3 = __ballot(s3);
                    if (lane == 0) {
                        MSK[t*4+0] = b0; MSK[t*4+1] = b1;
                        MSK[t*4+2] = b2; MSK[t*4+3] = b3;
                    }
                    v.x = s0 ? 0.f : v.x;  v.y = s1 ? 0.f : v.y;
                    v.z = s2 ? 0.f : v.z;  v.w = s3 ? 0.f : v.w;
                }
                if (s < 7) *(float4*)&LB[LB_V1 + lane*4] = v;
            }
            __syncthreads();
        }
        // ---- fc2 sparse: acc2 = sum over set spike bits of W2 rows ----
        // d ascending; conditional adds of exact zeros == dense fma(0/1) fp.
        float2 a2[8];
        #pragma unroll
        for (int r = 0; r < 8; ++r) a2[r] = make_float2(0.f, 0.f);
        #pragma unroll
        for (int r = 0; r < 8; ++r) {
            int t = row0 + r;
            unsigned long long m0 = rfl64(MSK[t*4+0]);
            unsigned long long m1 = rfl64(MSK[t*4+1]);
            unsigned long long m2 = rfl64(MSK[t*4+2]);
            unsigned long long m3 = rfl64(MSK[t*4+3]);
            unsigned long long mm = m0 | m1 | m2 | m3;
            while (mm) {
                int i = __builtin_ctzll(mm);
                mm &= mm - 1;
                const float* wrow = W2g + (size_t)i * 512;   // d = 4i + j
                float2 w0 = ((const float2*)(wrow      ))[lane];
                float2 w1 = ((const float2*)(wrow + 128))[lane];
                float2 w2 = ((const float2*)(wrow + 256))[lane];
                float2 w3 = ((const float2*)(wrow + 384))[lane];
                unsigned long long bit = 1ull << i;
                a2[r].x += (m0 & bit) ? w0.x : 0.f;  a2[r].y += (m0 & bit) ? w0.y : 0.f;
                a2[r].x += (m1 & bit) ? w1.x : 0.f;  a2[r].y += (m1 & bit) ? w1.y : 0.f;
                a2[r].x += (m2 & bit) ? w2.x : 0.f;  a2[r].y += (m2 & bit) ? w2.y : 0.f;
                a2[r].x += (m3 & bit) ? w3.x : 0.f;  a2[r].y += (m3 & bit) ? w3.y : 0.f;
            }
        }
        // ---- LN2 (round-2 tree) -> Y stays in a2 ----
        {
            float2 bv  = ((const float2*)(fc2b + l*128))[lane];
            float2 gv  = ((const float2*)(n2g  + l*128))[lane];
            float2 btv = ((const float2*)(n2b  + l*128))[lane];
            #pragma unroll
            for (int r = 0; r < 8; ++r) {
                float2 a = a2[r];
                a.x += bv.x; a.y += bv.y;
                float s = a.x + a.y;
                #pragma unroll
                for (int m = 1; m < 64; m <<= 1) s += __shfl_xor(s, m, 64);
                float mean = s * (1.0f/128.0f);
                float dx = a.x - mean, dy = a.y - mean;
                float q = dx*dx + dy*dy;
                #pragma unroll
                for (int m = 1; m < 64; m <<= 1) q += __shfl_xor(q, m, 64);
                float inv = 1.0f / sqrtf(q * (1.0f/128.0f) + 1e-5f);
                a2[r].x = dx*inv*gv.x + btv.x;
                a2[r].y = dy*inv*gv.y + btv.y;
            }
        }
        // prefetch next layer's fc1 W chunk 0 (latency hides under LIF2)
        if (l < 3) {
            const v4f* Wn = (const v4f*)(fc1w + (size_t)(l+1) * 32768);
            wr0 = Wn[tid]; wr1 = Wn[tid+512]; wr2 = Wn[tid+1024]; wr3 = Wn[tid+1536];
        }
        // ---- LIF2 + residual: serial wave-handoff; writes X(l+1), out ----
        #pragma unroll 1
        for (int s = 0; s < 8; ++s) {
            if (wave == s) {
                float2 v;
                if (s == 0) v = make_float2(0.f, 0.f);
                else        v = *(float2*)&LB[LB_V2 + lane*2];
                #pragma unroll
                for (int i = 0; i < 8; ++i) {
                    int t = s*8 + i;
                    float2 y = a2[i];
                    v.x += (y.x - v.x) * 0.5f;
                    v.y += (y.y - v.y) * 0.5f;
                    bool s0 = v.x >= 1.f, s1 = v.y >= 1.f;
                    float2 xv = ((const float2*)(Xl + (size_t)t*128))[lane];
                    float2 xn;
                    xn.x = xv.x + (s0 ? 1.f : 0.f);
                    xn.y = xv.y + (s1 ? 1.f : 0.f);
                    ((float2*)(Xo + (size_t)t*128))[lane] = xn;
                    v.x = s0 ? 0.f : v.x;
                    v.y = s1 ? 0.f : v.y;
                    if (l == 3 && t == 63)
                        ((float2*)(out + b*128))[lane] = xn;   // row t=2047
                }
                if (s < 7) *(float2*)&LB[LB_V2 + lane*2] = v;
            }
            __syncthreads();
        }
    }
}

extern "C" void kernel_launch(void* const* d_in, const int* in_sizes, int n_in,
                              void* d_out, int out_size, void* d_ws, size_t ws_size,
                              hipStream_t stream) {
    const float* hist = (const float*)d_in[0];
    const float* pw1  = (const float*)d_in[1];
    const float* pb1  = (const float*)d_in[2];
    const float* pw2  = (const float*)d_in[3];
    const float* pb2  = (const float*)d_in[4];
    const float* fc1w = (const float*)d_in[5];
    const float* fc1b = (const float*)d_in[6];
    const float* n1g  = (const float*)d_in[7];
    const float* n1b  = (const float*)d_in[8];
    const float* fc2w = (const float*)d_in[9];
    const float* fc2b = (const float*)d_in[10];
    const float* n2g  = (const float*)d_in[11];
    const float* n2b  = (const float*)d_in[12];
    float* out = (float*)d_out;

    float* Xb = (float*)d_ws;        // 5 regions x [NR,128] f32 = 10 MiB

    fused_kernel<<<64, 512, 0, stream>>>(hist, pw1, pb1, pw2, pb2,
                                         fc1w, fc1b, n1g, n1b,
                                         fc2w, fc2b, n2g, n2b,
                                         (const float*)Xb, Xb, out);
}